// Round 1
// baseline (375638.818 us; speedup 1.0000x reference)
//
#include <hip/hip_runtime.h>
#include <stdint.h>

typedef unsigned int uint32;

#define T_SEQ 8192
#define NWG_L 128   // workgroups per layer
#define RING  8

// ---------------- device helpers ----------------
__device__ __forceinline__ float bflo(uint32 u){ return __uint_as_float(u << 16); }
__device__ __forceinline__ float bfhi(uint32 u){ return __uint_as_float(u & 0xffff0000u); }

__device__ __forceinline__ unsigned short f2bf(float f){
  uint32 u = __float_as_uint(f);
  u += 0x7fffu + ((u >> 16) & 1u);          // round-to-nearest-even
  return (unsigned short)(u >> 16);
}

__device__ __forceinline__ void mac8(float& a, uint4 w,
    float h0,float h1,float h2,float h3,float h4,float h5,float h6,float h7){
  a = fmaf(bflo(w.x), h0, a); a = fmaf(bfhi(w.x), h1, a);
  a = fmaf(bflo(w.y), h2, a); a = fmaf(bfhi(w.y), h3, a);
  a = fmaf(bflo(w.z), h4, a); a = fmaf(bfhi(w.z), h5, a);
  a = fmaf(bflo(w.w), h6, a); a = fmaf(bfhi(w.w), h7, a);
}

__device__ __forceinline__ void spin_ge(const uint32* p, uint32 tgt){
  uint32 g = 0;
  while (__hip_atomic_load(p, __ATOMIC_ACQUIRE, __HIP_MEMORY_SCOPE_AGENT) < tgt) {
    __builtin_amdgcn_s_sleep(2);
    if (++g > 30000000u) break;             // safety valve: deadlock -> garbage, not hang
  }
}

// ---------------- persistent 2-layer LSTM ----------------
// grid = 256 WGs x 256 thr, 1 WG/CU. WG 0..127: layer0 (units 8*wg..+8);
// WG 128..255: layer1. Per WG: 32 gate rows (4 gates x 8 units).
// wave rg (tid>>6) = gate rg; lane c (tid&63) = column chunk.
// LDS (dynamic): L0: Whh0[32][1024]bf16 @0 (64KB), Wih0[32][304]bf16 @65536 (19KB)
//                L1: [Wih1|Whh1][32][2048]bf16 @0 (128KB)
//                both: red[32][8]f32 @131072, bias[32]f32 @132096
// Piece-interleaved rows: within a row, cols are stored so lane c's 16B piece j
// sits at byte j*1024 + c*16  -> banks 4c mod 32, conflict-free ds_read_b128.
extern "C" __global__ void __launch_bounds__(256)
lstm_persistent(const float* __restrict__ quote,
                const float* __restrict__ Wih0, const float* __restrict__ Whh0,
                const float* __restrict__ bih0, const float* __restrict__ bhh0,
                const float* __restrict__ Wih1, const float* __restrict__ Whh1,
                const float* __restrict__ bih1, const float* __restrict__ bhh1,
                float* __restrict__ h1ring, float* __restrict__ h2ring,
                uint32* h1cnt, uint32* h2cnt)
{
  extern __shared__ char smem[];
  float* red   = (float*)(smem + 131072);
  float* biasL = (float*)(smem + 132096);

  const int tid = threadIdx.x;
  const int rg  = tid >> 6;
  const int c   = tid & 63;
  const int wg  = blockIdx.x;
  const bool isL1 = (wg >= NWG_L);
  const int lwg = isL1 ? (wg - NWG_L) : wg;
  const int unit_base = lwg * 8;

  // ---- one-time weight fill: fp32 global -> bf16 LDS (piece-interleaved) ----
  if (!isL1) {
    for (int gi = tid; gi < 4096; gi += 256) {           // Whh0: 32 rows x 128 groups
      int r  = gi >> 7;
      int x0 = (gi & 127) << 3;
      int R  = (r >> 3) * 1024 + unit_base + (r & 7);
      const float* s = Whh0 + (size_t)R * 1024 + x0;
      unsigned short* d = (unsigned short*)(smem + r*2048 + ((x0>>3)&1)*1024 + (x0>>4)*16);
      #pragma unroll
      for (int m = 0; m < 8; ++m) d[m] = f2bf(s[m]);
    }
    for (int gi = tid; gi < 1216; gi += 256) {           // Wih0: 32 rows x 38 groups (pad->304)
      int r  = gi / 38;
      int g  = gi - r * 38;
      int x0 = g << 3;
      int R  = (r >> 3) * 1024 + unit_base + (r & 7);
      unsigned short* d = (unsigned short*)(smem + 65536 + r*608 + x0*2);
      #pragma unroll
      for (int m = 0; m < 8; ++m) {
        int x = x0 + m;
        d[m] = f2bf(x < 300 ? Wih0[(size_t)R * 300 + x] : 0.0f);
      }
    }
    if (tid < 32) {
      int R = (tid >> 3) * 1024 + unit_base + (tid & 7);
      biasL[tid] = bih0[R] + bhh0[R];
    }
  } else {
    for (int gi = tid; gi < 8192; gi += 256) {           // [Wih1|Whh1]: 32 rows x 256 groups
      int r  = gi >> 8;
      int x0 = (gi & 255) << 3;
      int R  = (r >> 3) * 1024 + unit_base + (r & 7);
      const float* s = (x0 < 1024) ? (Wih1 + (size_t)R*1024 + x0)
                                   : (Whh1 + (size_t)R*1024 + (x0 - 1024));
      unsigned short* d = (unsigned short*)(smem + r*4096 + ((x0>>3)&3)*1024 + (x0>>5)*16);
      #pragma unroll
      for (int m = 0; m < 8; ++m) d[m] = f2bf(s[m]);
    }
    if (tid < 32) {
      int R = (tid >> 3) * 1024 + unit_base + (tid & 7);
      biasL[tid] = bih1[R] + bhh1[R];
    }
  }
  __syncthreads();

  float c_state = 0.0f;   // cell state of unit (tid) for tid<8

  for (int t = 0; t < T_SEQ; ++t) {
    const int slot = t & 7;
    float acc[8];
    #pragma unroll
    for (int i = 0; i < 8; ++i) acc[i] = 0.0f;

    // ---- L0 x-part first: independent of any wait, hides sync latency ----
    if (!isL1 && c < 38) {
      float xv[8];
      int x0 = c << 3;
      const float* xr = quote + (size_t)t * 300 + x0;
      #pragma unroll
      for (int m = 0; m < 8; ++m) xv[m] = (x0 + m < 300) ? xr[m] : 0.0f;
      #pragma unroll
      for (int r8 = 0; r8 < 8; ++r8) {
        uint4 w = *(const uint4*)(smem + 65536 + (rg*8 + r8)*608 + (c << 4));
        mac8(acc[r8], w, xv[0],xv[1],xv[2],xv[3],xv[4],xv[5],xv[6],xv[7]);
      }
    }

    // ---- dataflow waits: 8 parallel sub-counter spinners (monotonic targets) ----
    if (!isL1) {
      if (t > 0 && tid < 8)
        spin_ge(h1cnt + ((t-1)&7)*256 + tid*32, 16u*((uint32)((t-1)>>3) + 1u));
    } else {
      if (tid < 8)
        spin_ge(h1cnt + slot*256 + tid*32, 16u*((uint32)(t>>3) + 1u));
      else if (tid < 16 && t > 0)
        spin_ge(h2cnt + ((t-1)&7)*256 + (tid-8)*32, 16u*((uint32)((t-1)>>3) + 1u));
    }
    __syncthreads();

    // ---- recurrent matvec: h via AGENT-scope (sc1) loads, weights from LDS ----
    if (!isL1) {
      float hv[16];
      if (t > 0) {
        const float* hp = h1ring + ((t-1)&7)*1024 + (c << 4);
        #pragma unroll
        for (int k = 0; k < 16; ++k)
          hv[k] = __hip_atomic_load(hp + k, __ATOMIC_RELAXED, __HIP_MEMORY_SCOPE_AGENT);
      } else {
        #pragma unroll
        for (int k = 0; k < 16; ++k) hv[k] = 0.0f;
      }
      #pragma unroll
      for (int r8 = 0; r8 < 8; ++r8) {
        const char* rowb = smem + (rg*8 + r8)*2048;
        uint4 w0 = *(const uint4*)(rowb + (c << 4));
        uint4 w1 = *(const uint4*)(rowb + 1024 + (c << 4));
        mac8(acc[r8], w0, hv[0],hv[1],hv[2],hv[3],hv[4],hv[5],hv[6],hv[7]);
        mac8(acc[r8], w1, hv[8],hv[9],hv[10],hv[11],hv[12],hv[13],hv[14],hv[15]);
      }
    } else {
      float hv[32];
      if (c < 32) {                               // cols 0..1023: Wih1 * h1[t]
        const float* hp = h1ring + slot*1024 + (c << 5);
        #pragma unroll
        for (int k = 0; k < 32; ++k)
          hv[k] = __hip_atomic_load(hp + k, __ATOMIC_RELAXED, __HIP_MEMORY_SCOPE_AGENT);
      } else if (t > 0) {                         // cols 1024..2047: Whh1 * h2[t-1]
        const float* hp = h2ring + ((t-1)&7)*1024 + ((c - 32) << 5);
        #pragma unroll
        for (int k = 0; k < 32; ++k)
          hv[k] = __hip_atomic_load(hp + k, __ATOMIC_RELAXED, __HIP_MEMORY_SCOPE_AGENT);
      } else {
        #pragma unroll
        for (int k = 0; k < 32; ++k) hv[k] = 0.0f;
      }
      #pragma unroll
      for (int r8 = 0; r8 < 8; ++r8) {
        const char* rowb = smem + (rg*8 + r8)*4096;
        #pragma unroll
        for (int j = 0; j < 4; ++j) {
          uint4 w = *(const uint4*)(rowb + j*1024 + (c << 4));
          mac8(acc[r8], w, hv[8*j],hv[8*j+1],hv[8*j+2],hv[8*j+3],
                           hv[8*j+4],hv[8*j+5],hv[8*j+6],hv[8*j+7]);
        }
      }
    }

    // ---- reduce: xor-8/16/32 (permlane/DPP class) -> lanes 0..7 hold octave sums ----
    #pragma unroll
    for (int r8 = 0; r8 < 8; ++r8) {
      acc[r8] += __shfl_xor(acc[r8], 8);
      acc[r8] += __shfl_xor(acc[r8], 16);
      acc[r8] += __shfl_xor(acc[r8], 32);
    }
    if (c < 8) {
      #pragma unroll
      for (int r8 = 0; r8 < 8; ++r8) red[(rg*8 + r8)*8 + c] = acc[r8];
    }
    __syncthreads();

    // ---- back-pressure: L0 must not overwrite h1 slot t&7 until L1 consumed h1[t-8] ----
    if (!isL1 && t >= 8 && tid < 8)
      spin_ge(h2cnt + ((t-8)&7)*256 + tid*32, 16u*((uint32)((t-8)>>3) + 1u));
    __syncthreads();

    // ---- gates, state update, publish (one thread per hidden unit) ----
    if (tid < 8) {
      float gs[4];
      #pragma unroll
      for (int g = 0; g < 4; ++g) {
        const float* rp = red + (g*8 + tid)*8;
        gs[g] = ((rp[0]+rp[1]) + (rp[2]+rp[3])) + ((rp[4]+rp[5]) + (rp[6]+rp[7]))
              + biasL[g*8 + tid];
      }
      float ig = 1.0f / (1.0f + expf(-gs[0]));
      float fg = 1.0f / (1.0f + expf(-gs[1]));
      float gg = tanhf(gs[2]);
      float og = 1.0f / (1.0f + expf(-gs[3]));
      c_state = fg * c_state + ig * gg;
      float h = og * tanhf(c_state);
      float* ring = isL1 ? h2ring : h1ring;
      __hip_atomic_store(ring + slot*1024 + unit_base + tid, h,
                         __ATOMIC_RELAXED, __HIP_MEMORY_SCOPE_AGENT);
    }
    __syncthreads();                 // drains all lanes' sc1 stores (vmcnt 0 before s_barrier)
    if (tid == 0) {
      uint32* cnt = isL1 ? h2cnt : h1cnt;
      __hip_atomic_fetch_add(cnt + slot*256 + (lwg & 7)*32, 1u,
                             __ATOMIC_RELEASE, __HIP_MEMORY_SCOPE_AGENT);
    }
  }
}

// ---------------- tiny MLP head ----------------
extern "C" __global__ void __launch_bounds__(256)
head_fc(const float* __restrict__ W, const float* __restrict__ b,
        const float* __restrict__ xin, float* __restrict__ y, int n_in)
{
  __shared__ float sred[256];
  const int i = blockIdx.x;
  float p = 0.0f;
  for (int k = threadIdx.x; k < n_in; k += 256)
    p = fmaf(W[(size_t)i * n_in + k], xin[k], p);
  sred[threadIdx.x] = p;
  __syncthreads();
  for (int s = 128; s > 0; s >>= 1) {
    if (threadIdx.x < s) sred[threadIdx.x] += sred[threadIdx.x + s];
    __syncthreads();
  }
  if (threadIdx.x == 0) y[i] = fmaxf(sred[0] + b[i], 0.0f);
}

extern "C" __global__ void __launch_bounds__(64)
head_out(const float* __restrict__ W2, const float* __restrict__ b2,
         const float* __restrict__ y1, float* __restrict__ out)
{
  const int l = threadIdx.x;
  float p0 = 0.0f, p1 = 0.0f, p2 = 0.0f;
  for (int k = l; k < 512; k += 64) {
    float v = y1[k];
    p0 = fmaf(W2[k],        v, p0);
    p1 = fmaf(W2[512 + k],  v, p1);
    p2 = fmaf(W2[1024 + k], v, p2);
  }
  #pragma unroll
  for (int m = 1; m < 64; m <<= 1) {
    p0 += __shfl_xor(p0, m);
    p1 += __shfl_xor(p1, m);
    p2 += __shfl_xor(p2, m);
  }
  if (l == 0) {
    float z0 = p0 + b2[0], z1 = p1 + b2[1], z2 = p2 + b2[2];
    float mx = fmaxf(z0, fmaxf(z1, z2));
    float lse = mx + logf(expf(z0 - mx) + expf(z1 - mx) + expf(z2 - mx));
    out[0] = z0 - lse; out[1] = z1 - lse; out[2] = z2 - lse;
  }
}

// ---------------- host ----------------
extern "C" void kernel_launch(void* const* d_in, const int* in_sizes, int n_in,
                              void* d_out, int out_size, void* d_ws, size_t ws_size,
                              hipStream_t stream)
{
  (void)in_sizes; (void)n_in; (void)out_size; (void)ws_size;
  const float* quote = (const float*)d_in[0];
  const float* Wih0  = (const float*)d_in[1];
  const float* Whh0  = (const float*)d_in[2];
  const float* bih0  = (const float*)d_in[3];
  const float* bhh0  = (const float*)d_in[4];
  const float* Wih1  = (const float*)d_in[5];
  const float* Whh1  = (const float*)d_in[6];
  const float* bih1  = (const float*)d_in[7];
  const float* bhh1  = (const float*)d_in[8];
  const float* W0    = (const float*)d_in[9];
  const float* b0    = (const float*)d_in[10];
  const float* W1    = (const float*)d_in[11];
  const float* b1    = (const float*)d_in[12];
  const float* W2    = (const float*)d_in[13];
  const float* b2    = (const float*)d_in[14];

  char* ws = (char*)d_ws;
  float*  h1ring = (float*)(ws + 0);          // 8 x 1024 f32
  float*  h2ring = (float*)(ws + 32768);      // 8 x 1024 f32
  uint32* h1cnt  = (uint32*)(ws + 65536);     // 8 slots x 8 subs x 128B
  uint32* h2cnt  = (uint32*)(ws + 73728);
  float*  y0     = (float*)(ws + 81920);      // 512 f32
  float*  y1     = (float*)(ws + 83968);      // 512 f32

  // counters must be zeroed every call (ws poisoned once, never re-poisoned)
  hipMemsetAsync(ws + 65536, 0, 16384, stream);

  hipFuncSetAttribute((const void*)lstm_persistent,
                      hipFuncAttributeMaxDynamicSharedMemorySize, 135168);

  void* args[] = { (void*)&quote, (void*)&Wih0, (void*)&Whh0, (void*)&bih0, (void*)&bhh0,
                   (void*)&Wih1, (void*)&Whh1, (void*)&bih1, (void*)&bhh1,
                   (void*)&h1ring, (void*)&h2ring, (void*)&h1cnt, (void*)&h2cnt };
  hipLaunchCooperativeKernel((const void*)lstm_persistent, dim3(256), dim3(256),
                             args, 135168u, stream);

  // h2[T-1] lives in ring slot (8191 & 7) = 7
  head_fc<<<512, 256, 0, stream>>>(W0, b0, h2ring + 7*1024, y0, 1024);
  head_fc<<<512, 256, 0, stream>>>(W1, b1, y0, y1, 512);
  head_out<<<1, 64, 0, stream>>>(W2, b2, y1, (float*)d_out);
}

// Round 3
// 59153.839 us; speedup vs baseline: 6.3502x; 6.3502x over previous
//
#include <hip/hip_runtime.h>
#include <stdint.h>

typedef unsigned int uint32;
typedef unsigned long long uint64;

#define T_SEQ 8192
#define NWG_L 128   // workgroups per layer

// ---------------- device helpers ----------------
__device__ __forceinline__ float bflo(uint32 u){ return __uint_as_float(u << 16); }
__device__ __forceinline__ float bfhi(uint32 u){ return __uint_as_float(u & 0xffff0000u); }

__device__ __forceinline__ unsigned short f2bf(float f){
  uint32 u = __float_as_uint(f);
  u += 0x7fffu + ((u >> 16) & 1u);          // round-to-nearest-even
  return (unsigned short)(u >> 16);
}

__device__ __forceinline__ void mac8(float& a, uint4 w,
    float h0,float h1,float h2,float h3,float h4,float h5,float h6,float h7){
  a = fmaf(bflo(w.x), h0, a); a = fmaf(bfhi(w.x), h1, a);
  a = fmaf(bflo(w.y), h2, a); a = fmaf(bfhi(w.y), h3, a);
  a = fmaf(bflo(w.z), h4, a); a = fmaf(bfhi(w.z), h5, a);
  a = fmaf(bflo(w.w), h6, a); a = fmaf(bfhi(w.w), h7, a);
}

__device__ __forceinline__ uint64 ald64(const uint64* p){
  return __hip_atomic_load(p, __ATOMIC_RELAXED, __HIP_MEMORY_SCOPE_AGENT);
}
__device__ __forceinline__ void ast64(uint64* p, uint64 v){
  __hip_atomic_store(p, v, __ATOMIC_RELAXED, __HIP_MEMORY_SCOPE_AGENT);
}
__device__ __forceinline__ uint32 ald32(const uint32* p){
  return __hip_atomic_load(p, __ATOMIC_RELAXED, __HIP_MEMORY_SCOPE_AGENT);
}
__device__ __forceinline__ void ast32(uint32* p, uint32 v){
  __hip_atomic_store(p, v, __ATOMIC_RELAXED, __HIP_MEMORY_SCOPE_AGENT);
}

__device__ __forceinline__ float val_of(uint64 w){ return __uint_as_float((uint32)(w >> 32)); }

// ---------------- persistent 2-layer LSTM, 64-bit tagged fp32 dataflow ----------------
// grid = 256 WGs x 256 thr, 1 WG/CU. WG 0..127: layer0 (8 units each); 128..255: layer1.
// Published element = (fp32(h)<<32) | (t+1): ONE relaxed agent 8B atomic. Self-validating,
// fp32-exact, no fences. h1 ring depth 16, h2 ring depth 4 (intra-layer WG skew <= 1 step
// because every WG reads ALL units of its layer each step). L1 lag vs L0 is bounded by a
// watermark: L1-WG0 stores prog=t+1 each step; L0 stalls step s until prog >= s-12.
// LDS: L0: Whh0[32 rows][2 pieces x 64 x 16B] @0, Wih0[32][608B] @65536
//      L1: concat[Wih1|Whh1][32 rows][4 pieces x 64 x 16B] @0 (128KB)
//      both: red[32][8]f32 @131072, bias[32]f32 @132096
extern "C" __global__ void __launch_bounds__(256)
lstm_persistent(const float* __restrict__ quote,
                const float* __restrict__ Wih0, const float* __restrict__ Whh0,
                const float* __restrict__ bih0, const float* __restrict__ bhh0,
                const float* __restrict__ Wih1, const float* __restrict__ Whh1,
                const float* __restrict__ bih1, const float* __restrict__ bhh1,
                uint64* __restrict__ h1r, uint64* __restrict__ h2r,
                uint32* __restrict__ prog, float* __restrict__ h2last)
{
  extern __shared__ char smem[];
  float* red   = (float*)(smem + 131072);
  float* biasL = (float*)(smem + 132096);

  const int tid = threadIdx.x;
  const int rg  = tid >> 6;
  const int c   = tid & 63;
  const int wg  = blockIdx.x;
  const bool isL1 = (wg >= NWG_L);
  const int lwg = isL1 ? (wg - NWG_L) : wg;
  const int unit_base = lwg * 8;

  // ---- one-time weight fill: fp32 global -> bf16 LDS (piece-interleaved) ----
  if (!isL1) {
    for (int gi = tid; gi < 4096; gi += 256) {           // Whh0: 32 rows x 128 groups of 8
      int r  = gi >> 7;
      int x0 = (gi & 127) << 3;
      int R  = (r >> 3) * 1024 + unit_base + (r & 7);
      const float* s = Whh0 + (size_t)R * 1024 + x0;
      unsigned short* d = (unsigned short*)(smem + r*2048 + ((x0>>3)&1)*1024 + (x0>>4)*16);
      #pragma unroll
      for (int m = 0; m < 8; ++m) d[m] = f2bf(s[m]);
    }
    for (int gi = tid; gi < 1216; gi += 256) {           // Wih0: 32 rows x 38 groups (pad->304)
      int r  = gi / 38;
      int g  = gi - r * 38;
      int x0 = g << 3;
      int R  = (r >> 3) * 1024 + unit_base + (r & 7);
      unsigned short* d = (unsigned short*)(smem + 65536 + r*608 + x0*2);
      #pragma unroll
      for (int m = 0; m < 8; ++m) {
        int x = x0 + m;
        d[m] = f2bf(x < 300 ? Wih0[(size_t)R * 300 + x] : 0.0f);
      }
    }
    if (tid < 32) {
      int R = (tid >> 3) * 1024 + unit_base + (tid & 7);
      biasL[tid] = bih0[R] + bhh0[R];
    }
  } else {
    for (int gi = tid; gi < 8192; gi += 256) {           // concat: 32 rows x 256 groups of 8
      int r  = gi >> 8;
      int x0 = (gi & 255) << 3;                          // concat col 0..2047
      int R  = (r >> 3) * 1024 + unit_base + (r & 7);
      const float* s = (x0 < 1024) ? (Wih1 + (size_t)R*1024 + x0)
                                   : (Whh1 + (size_t)R*1024 + (x0 - 1024));
      int p  = x0 >> 9;                                  // piece 0..3
      int cs = (x0 & 511) >> 3;                          // lane slot 0..63
      unsigned short* d = (unsigned short*)(smem + r*4096 + p*1024 + cs*16);
      #pragma unroll
      for (int m = 0; m < 8; ++m) d[m] = f2bf(s[m]);
    }
    if (tid < 32) {
      int R = (tid >> 3) * 1024 + unit_base + (tid & 7);
      biasL[tid] = bih1[R] + bhh1[R];
    }
  }
  __syncthreads();

  float c_state = 0.0f;       // cell state of unit (tid) for tid<8
  uint32 prog_seen = 0;       // L0 publishers' cached view of L1 progress

  for (int t = 0; t < T_SEQ; ++t) {
    float acc[8];
    #pragma unroll
    for (int i = 0; i < 8; ++i) acc[i] = 0.0f;

    if (!isL1) {
      // ---- issue h1[t-1] loads first (tag = t), hide latency under x-part ----
      uint64 up[16];
      const uint64* hp = h1r + (size_t)((t-1) & 15) * 1024 + (c << 4);
      if (t > 0) {
        #pragma unroll
        for (int k = 0; k < 16; ++k) up[k] = ald64(hp + k);
      }
      // ---- x-part from LDS (independent of recurrence) ----
      if (c < 38) {
        float xv[8];
        int x0 = c << 3;
        const float* xr = quote + (size_t)t * 300 + x0;
        #pragma unroll
        for (int m = 0; m < 8; ++m) xv[m] = (x0 + m < 300) ? xr[m] : 0.0f;
        #pragma unroll
        for (int r8 = 0; r8 < 8; ++r8) {
          uint4 w = *(const uint4*)(smem + 65536 + (rg*8 + r8)*608 + (c << 4));
          mac8(acc[r8], w, xv[0],xv[1],xv[2],xv[3],xv[4],xv[5],xv[6],xv[7]);
        }
      }
      if (t > 0) {
        const uint32 want = (uint32)t;
        uint32 guard = 0;
        for (;;) {
          bool ok = true;
          #pragma unroll
          for (int k = 0; k < 16; ++k) ok &= ((uint32)up[k] == want);
          if (ok) break;
          __builtin_amdgcn_s_sleep(2);
          if (++guard > 20000000u) break;      // deadlock -> garbage, not hang
          #pragma unroll
          for (int k = 0; k < 16; ++k) up[k] = ald64(hp + k);
        }
        #pragma unroll
        for (int r8 = 0; r8 < 8; ++r8) {
          const char* rowb = smem + (rg*8 + r8)*2048;
          uint4 w0 = *(const uint4*)(rowb + (c << 4));
          uint4 w1 = *(const uint4*)(rowb + 1024 + (c << 4));
          mac8(acc[r8], w0, val_of(up[0]),val_of(up[1]),val_of(up[2]),val_of(up[3]),
                            val_of(up[4]),val_of(up[5]),val_of(up[6]),val_of(up[7]));
          mac8(acc[r8], w1, val_of(up[8]),val_of(up[9]),val_of(up[10]),val_of(up[11]),
                            val_of(up[12]),val_of(up[13]),val_of(up[14]),val_of(up[15]));
        }
      }
    } else {
      // ---- phase A: own h2[t-1] (tag=t, ready early); phase B: h1[t] (tag=t+1) ----
      uint64 ua[16], ub[16];
      const uint64* h2p = h2r + (size_t)((t-1) & 3) * 1024 + (c << 3);
      const uint64* h1p = h1r + (size_t)(t & 15) * 1024 + (c << 3);
      if (t > 0) {
        #pragma unroll
        for (int k = 0; k < 8; ++k) { ua[k] = ald64(h2p + k); ua[8+k] = ald64(h2p + 512 + k); }
      }
      #pragma unroll
      for (int k = 0; k < 8; ++k) { ub[k] = ald64(h1p + k); ub[8+k] = ald64(h1p + 512 + k); }

      if (t > 0) {
        const uint32 want = (uint32)t;
        uint32 guard = 0;
        for (;;) {
          bool ok = true;
          #pragma unroll
          for (int k = 0; k < 16; ++k) ok &= ((uint32)ua[k] == want);
          if (ok) break;
          __builtin_amdgcn_s_sleep(2);
          if (++guard > 20000000u) break;
          #pragma unroll
          for (int k = 0; k < 8; ++k) { ua[k] = ald64(h2p + k); ua[8+k] = ald64(h2p + 512 + k); }
        }
        #pragma unroll
        for (int r8 = 0; r8 < 8; ++r8) {       // pieces 2,3: Whh1 * h2[t-1]
          const char* rowb = smem + (rg*8 + r8)*4096;
          uint4 w2 = *(const uint4*)(rowb + 2048 + (c << 4));
          uint4 w3 = *(const uint4*)(rowb + 3072 + (c << 4));
          mac8(acc[r8], w2, val_of(ua[0]),val_of(ua[1]),val_of(ua[2]),val_of(ua[3]),
                            val_of(ua[4]),val_of(ua[5]),val_of(ua[6]),val_of(ua[7]));
          mac8(acc[r8], w3, val_of(ua[8]),val_of(ua[9]),val_of(ua[10]),val_of(ua[11]),
                            val_of(ua[12]),val_of(ua[13]),val_of(ua[14]),val_of(ua[15]));
        }
      }
      {
        const uint32 want = (uint32)(t + 1);
        uint32 guard = 0;
        for (;;) {
          bool ok = true;
          #pragma unroll
          for (int k = 0; k < 16; ++k) ok &= ((uint32)ub[k] == want);
          if (ok) break;
          __builtin_amdgcn_s_sleep(2);
          if (++guard > 20000000u) break;
          #pragma unroll
          for (int k = 0; k < 8; ++k) { ub[k] = ald64(h1p + k); ub[8+k] = ald64(h1p + 512 + k); }
        }
        #pragma unroll
        for (int r8 = 0; r8 < 8; ++r8) {       // pieces 0,1: Wih1 * h1[t]
          const char* rowb = smem + (rg*8 + r8)*4096;
          uint4 w0 = *(const uint4*)(rowb + (c << 4));
          uint4 w1 = *(const uint4*)(rowb + 1024 + (c << 4));
          mac8(acc[r8], w0, val_of(ub[0]),val_of(ub[1]),val_of(ub[2]),val_of(ub[3]),
                            val_of(ub[4]),val_of(ub[5]),val_of(ub[6]),val_of(ub[7]));
          mac8(acc[r8], w1, val_of(ub[8]),val_of(ub[9]),val_of(ub[10]),val_of(ub[11]),
                            val_of(ub[12]),val_of(ub[13]),val_of(ub[14]),val_of(ub[15]));
        }
      }
    }

    // ---- reduce -> lanes 0..7 hold the 8 partials per gate row ----
    #pragma unroll
    for (int r8 = 0; r8 < 8; ++r8) {
      acc[r8] += __shfl_xor(acc[r8], 8);
      acc[r8] += __shfl_xor(acc[r8], 16);
      acc[r8] += __shfl_xor(acc[r8], 32);
    }
    if (c < 8) {
      #pragma unroll
      for (int r8 = 0; r8 < 8; ++r8) red[(rg*8 + r8)*8 + c] = acc[r8];
    }
    __syncthreads();

    // ---- gates, state update, tagged publish ----
    if (tid < 8) {
      float gs[4];
      #pragma unroll
      for (int g = 0; g < 4; ++g) {
        const float* rp = red + (g*8 + tid)*8;
        gs[g] = ((rp[0]+rp[1]) + (rp[2]+rp[3])) + ((rp[4]+rp[5]) + (rp[6]+rp[7]))
              + biasL[g*8 + tid];
      }
      float ig = 1.0f / (1.0f + expf(-gs[0]));
      float fg = 1.0f / (1.0f + expf(-gs[1]));
      float gg = tanhf(gs[2]);
      float og = 1.0f / (1.0f + expf(-gs[3]));
      c_state = fg * c_state + ig * gg;
      float h = og * tanhf(c_state);
      uint64 pk = ((uint64)__float_as_uint(h) << 32) | (uint32)(t + 1);

      if (!isL1) {
        // back-pressure: publishing step t overwrites h1 gen t-16; all L1 WGs only
        // need gens >= prog-1, so require prog >= t-12 (margin 2). Cached in SGPR-land:
        // in steady state prog ~ t, so this issues no loads at all.
        if ((int)prog_seen < t - 12) {
          uint32 guard = 0;
          for (;;) {
            uint32 p = ald32(prog);
            if ((int)p >= t - 12) { prog_seen = p; break; }
            __builtin_amdgcn_s_sleep(2);
            if (++guard > 20000000u) break;
          }
        }
        ast64(h1r + (size_t)(t & 15) * 1024 + unit_base + tid, pk);
      } else {
        ast64(h2r + (size_t)(t & 3) * 1024 + unit_base + tid, pk);
        if (t == T_SEQ - 1) h2last[unit_base + tid] = h;
        if (lwg == 0 && tid == 0) ast32(prog, (uint32)(t + 1));  // L1 progress watermark
      }
    }
    __syncthreads();   // protect red[] against next iteration's writes
  }
}

// ---------------- tiny MLP head ----------------
extern "C" __global__ void __launch_bounds__(256)
head_fc(const float* __restrict__ W, const float* __restrict__ b,
        const float* __restrict__ xin, float* __restrict__ y, int n_in)
{
  __shared__ float sred[256];
  const int i = blockIdx.x;
  float p = 0.0f;
  for (int k = threadIdx.x; k < n_in; k += 256)
    p = fmaf(W[(size_t)i * n_in + k], xin[k], p);
  sred[threadIdx.x] = p;
  __syncthreads();
  for (int s = 128; s > 0; s >>= 1) {
    if (threadIdx.x < s) sred[threadIdx.x] += sred[threadIdx.x + s];
    __syncthreads();
  }
  if (threadIdx.x == 0) y[i] = fmaxf(sred[0] + b[i], 0.0f);
}

extern "C" __global__ void __launch_bounds__(64)
head_out(const float* __restrict__ W2, const float* __restrict__ b2,
         const float* __restrict__ y1, float* __restrict__ out)
{
  const int l = threadIdx.x;
  float p0 = 0.0f, p1 = 0.0f, p2 = 0.0f;
  for (int k = l; k < 512; k += 64) {
    float v = y1[k];
    p0 = fmaf(W2[k],        v, p0);
    p1 = fmaf(W2[512 + k],  v, p1);
    p2 = fmaf(W2[1024 + k], v, p2);
  }
  #pragma unroll
  for (int m = 1; m < 64; m <<= 1) {
    p0 += __shfl_xor(p0, m);
    p1 += __shfl_xor(p1, m);
    p2 += __shfl_xor(p2, m);
  }
  if (l == 0) {
    float z0 = p0 + b2[0], z1 = p1 + b2[1], z2 = p2 + b2[2];
    float mx = fmaxf(z0, fmaxf(z1, z2));
    float lse = mx + logf(expf(z0 - mx) + expf(z1 - mx) + expf(z2 - mx));
    out[0] = z0 - lse; out[1] = z1 - lse; out[2] = z2 - lse;
  }
}

// ---------------- host ----------------
extern "C" void kernel_launch(void* const* d_in, const int* in_sizes, int n_in,
                              void* d_out, int out_size, void* d_ws, size_t ws_size,
                              hipStream_t stream)
{
  (void)in_sizes; (void)n_in; (void)out_size; (void)ws_size;
  const float* quote = (const float*)d_in[0];
  const float* Wih0  = (const float*)d_in[1];
  const float* Whh0  = (const float*)d_in[2];
  const float* bih0  = (const float*)d_in[3];
  const float* bhh0  = (const float*)d_in[4];
  const float* Wih1  = (const float*)d_in[5];
  const float* Whh1  = (const float*)d_in[6];
  const float* bih1  = (const float*)d_in[7];
  const float* bhh1  = (const float*)d_in[8];
  const float* W0    = (const float*)d_in[9];
  const float* b0    = (const float*)d_in[10];
  const float* W1    = (const float*)d_in[11];
  const float* b1    = (const float*)d_in[12];
  const float* W2    = (const float*)d_in[13];
  const float* b2    = (const float*)d_in[14];

  char* ws = (char*)d_ws;
  uint64* h1r    = (uint64*)(ws + 0);          // [16][1024] tagged fp32 (128 KB)
  uint64* h2r    = (uint64*)(ws + 131072);     // [4][1024]  tagged fp32 (32 KB)
  uint32* prog   = (uint32*)(ws + 163840);     // L1 progress watermark (padded line)
  float*  h2last = (float*)(ws + 163968);      // 1024 f32
  float*  y0     = (float*)(ws + 168064);      // 512 f32
  float*  y1     = (float*)(ws + 170112);      // 512 f32

  // rings + watermark must be zero at every call start (tags are per-call unique)
  hipMemsetAsync(ws, 0, 163968, stream);

  hipFuncSetAttribute((const void*)lstm_persistent,
                      hipFuncAttributeMaxDynamicSharedMemorySize, 135168);

  void* args[] = { (void*)&quote, (void*)&Wih0, (void*)&Whh0, (void*)&bih0, (void*)&bhh0,
                   (void*)&Wih1, (void*)&Whh1, (void*)&bih1, (void*)&bhh1,
                   (void*)&h1r, (void*)&h2r, (void*)&prog, (void*)&h2last };
  hipLaunchCooperativeKernel((const void*)lstm_persistent, dim3(256), dim3(256),
                             args, 135168u, stream);

  head_fc<<<512, 256, 0, stream>>>(W0, b0, h2last, y0, 1024);
  head_fc<<<512, 256, 0, stream>>>(W1, b1, y0, y1, 512);
  head_out<<<1, 64, 0, stream>>>(W2, b2, y1, (float*)d_out);
}